// Round 4
// baseline (449.447 us; speedup 1.0000x reference)
//
#include <hip/hip_runtime.h>

// TemporalGCN: 2x GCNConv(64->64) + relu, global_mean_pool(64 graphs), linear 64->64.
// CSR-by-dst build -> y = (x@W)*dinv -> per-node gather-sum.
// R3: single-pass edge partition into 8 dst-stripe buckets (LDS-ranked, block-
// granular cursor atomics), then shard-local hist/scatter whose entire working
// set (bucket + counts + cursor + ssrc window) is L2-resident per XCD.

#define DF 64
#define SHARD_SHIFT 12   // 4096-node stripes; stripe & 7 = shard
#define TILE 1024        // edges per block in partition_kernel

// ---------------- P1: partition edges into 8 shard buckets ----------------

__global__ void partition_kernel(const int* __restrict__ src, const int* __restrict__ dst,
                                 int E, int quadOK,
                                 int* __restrict__ bsrc, int* __restrict__ bdst,
                                 int* __restrict__ shardCur, int cap) {
    __shared__ int lcnt[8];
    __shared__ int lbase[8];
    int tid = threadIdx.x;
    int e0 = blockIdx.x * TILE + tid * 4;
    int sv[4], dv[4], sh[4], rk[4], valid[4];
    if (quadOK && e0 + 3 < E) {
        int4 s4 = ((const int4*)src)[e0 >> 2];
        int4 d4 = ((const int4*)dst)[e0 >> 2];
        sv[0] = s4.x; sv[1] = s4.y; sv[2] = s4.z; sv[3] = s4.w;
        dv[0] = d4.x; dv[1] = d4.y; dv[2] = d4.z; dv[3] = d4.w;
        valid[0] = valid[1] = valid[2] = valid[3] = 1;
    } else {
#pragma unroll
        for (int j = 0; j < 4; j++) {
            int e = e0 + j;
            valid[j] = e < E;
            sv[j] = dv[j] = 0;
            if (valid[j]) { sv[j] = src[e]; dv[j] = dst[e]; }
        }
    }
    if (tid < 8) lcnt[tid] = 0;
    __syncthreads();
#pragma unroll
    for (int j = 0; j < 4; j++)
        if (valid[j]) {
            sh[j] = (dv[j] >> SHARD_SHIFT) & 7;
            rk[j] = atomicAdd(&lcnt[sh[j]], 1);
        }
    __syncthreads();
    if (tid < 8) lbase[tid] = atomicAdd(&shardCur[tid], lcnt[tid]);
    __syncthreads();
#pragma unroll
    for (int j = 0; j < 4; j++)
        if (valid[j]) {
            int p = lbase[sh[j]] + rk[j];
            if (p < cap) {
                int o = sh[j] * cap + p;
                bsrc[o] = sv[j];
                bdst[o] = dv[j];
            }
        }
}

// ---------------- P2: shard-local histogram ----------------

__global__ void hist2_kernel(const int* __restrict__ bdst, const int* __restrict__ shardCur,
                             int cap, int* __restrict__ counts) {
    int shard = blockIdx.x & 7;
    int nb = gridDim.x >> 3;
    int bi = blockIdx.x >> 3;
    int cnt = min(shardCur[shard], cap);
    const int* p = bdst + shard * cap;
    int stride = nb * blockDim.x;
    int i0 = bi * blockDim.x + threadIdx.x;
    int nqs = cnt >> 2;
    for (int i = i0; i < nqs; i += stride) {
        int4 d = ((const int4*)p)[i];
        atomicAdd(&counts[d.x], 1);
        atomicAdd(&counts[d.y], 1);
        atomicAdd(&counts[d.z], 1);
        atomicAdd(&counts[d.w], 1);
    }
    for (int i = 4 * nqs + i0; i < cnt; i += stride) atomicAdd(&counts[p[i]], 1);
}

// ---------------- P3: shard-local scatter (counting sort) ----------------

__global__ void scatter2_kernel(const int* __restrict__ bsrc, const int* __restrict__ bdst,
                                const int* __restrict__ shardCur, int cap,
                                int* __restrict__ cursor, int* __restrict__ ssrc) {
    int shard = blockIdx.x & 7;
    int nb = gridDim.x >> 3;
    int bi = blockIdx.x >> 3;
    int cnt = min(shardCur[shard], cap);
    const int* ps = bsrc + shard * cap;
    const int* pd = bdst + shard * cap;
    int stride = nb * blockDim.x;
    int i0 = bi * blockDim.x + threadIdx.x;
    int nqs = cnt >> 2;
    for (int i = i0; i < nqs; i += stride) {
        int4 d = ((const int4*)pd)[i];
        int4 s = ((const int4*)ps)[i];
        ssrc[atomicAdd(&cursor[d.x], 1)] = s.x;
        ssrc[atomicAdd(&cursor[d.y], 1)] = s.y;
        ssrc[atomicAdd(&cursor[d.z], 1)] = s.z;
        ssrc[atomicAdd(&cursor[d.w], 1)] = s.w;
    }
    for (int i = 4 * nqs + i0; i < cnt; i += stride)
        ssrc[atomicAdd(&cursor[pd[i]], 1)] = ps[i];
}

// ---------------- scans ----------------

__global__ void scan_a(const int* __restrict__ counts, int* __restrict__ blockSums, int n) {
    __shared__ int lds[256];
    int base = blockIdx.x * 1024 + threadIdx.x * 4;
    int s = 0;
#pragma unroll
    for (int j = 0; j < 4; j++) {
        int i = base + j;
        if (i < n) s += counts[i];
    }
    lds[threadIdx.x] = s;
    __syncthreads();
    for (int off = 128; off > 0; off >>= 1) {
        if (threadIdx.x < off) lds[threadIdx.x] += lds[threadIdx.x + off];
        __syncthreads();
    }
    if (threadIdx.x == 0) blockSums[blockIdx.x] = lds[0];
}

// single block; B <= 256
__global__ void scan_b(const int* __restrict__ blockSums, int* __restrict__ blockOffsets,
                       int* __restrict__ offsets_end, int B) {
    __shared__ int lds[256];
    int v = (threadIdx.x < B) ? blockSums[threadIdx.x] : 0;
    lds[threadIdx.x] = v;
    __syncthreads();
    for (int off = 1; off < 256; off <<= 1) {
        int t = (threadIdx.x >= off) ? lds[threadIdx.x - off] : 0;
        __syncthreads();
        lds[threadIdx.x] += t;
        __syncthreads();
    }
    if (threadIdx.x < B) blockOffsets[threadIdx.x] = lds[threadIdx.x] - v;
    if (threadIdx.x == 255) offsets_end[0] = lds[255];  // total (= E)
}

// also emits dinv[i] = 1/sqrt(deg_in+1)
__global__ void scan_c(const int* __restrict__ counts, const int* __restrict__ blockOffsets,
                       int* __restrict__ offsets, int* __restrict__ cursor,
                       float* __restrict__ dinv, int n) {
    __shared__ int lds[256];
    int base = blockIdx.x * 1024 + threadIdx.x * 4;
    int v[4];
    int s = 0;
#pragma unroll
    for (int j = 0; j < 4; j++) {
        int i = base + j;
        v[j] = (i < n) ? counts[i] : 0;
        s += v[j];
    }
    lds[threadIdx.x] = s;
    __syncthreads();
    for (int off = 1; off < 256; off <<= 1) {
        int t = (threadIdx.x >= off) ? lds[threadIdx.x - off] : 0;
        __syncthreads();
        lds[threadIdx.x] += t;
        __syncthreads();
    }
    int run = blockOffsets[blockIdx.x] + lds[threadIdx.x] - s;
#pragma unroll
    for (int j = 0; j < 4; j++) {
        int i = base + j;
        if (i < n) {
            offsets[i] = run;
            cursor[i] = run;
            dinv[i] = 1.0f / sqrtf((float)(v[j] + 1));
            run += v[j];
        }
    }
}

// ---------------- per-layer compute ----------------

// Y[row][c] = (sum_k X[row][k] * W[k][c]) * dinv[row]; float4 per thread.
__global__ void gemm_scale(const float4* __restrict__ X4, const float4* __restrict__ W4,
                           const float* __restrict__ dinv, float4* __restrict__ Y4, int n) {
    __shared__ float4 Wl4[64][16];   // [k][c4]
    __shared__ float Xl[16][68];     // padded: conflict-free broadcast
    int tid = threadIdx.x;
    float4* Wf = &Wl4[0][0];
#pragma unroll
    for (int i = 0; i < 4; i++) {
        int idx = tid + i * 256;     // idx = k*16 + c4
        Wf[idx] = W4[idx];
    }
    int row0 = blockIdx.x * 16;
    int r = tid >> 4, c4 = tid & 15;
    {
        int row = row0 + r;
        float4 v = (row < n) ? X4[(size_t)row * 16 + c4] : float4{0.f, 0.f, 0.f, 0.f};
        Xl[r][c4 * 4 + 0] = v.x;
        Xl[r][c4 * 4 + 1] = v.y;
        Xl[r][c4 * 4 + 2] = v.z;
        Xl[r][c4 * 4 + 3] = v.w;
    }
    __syncthreads();
    float ax = 0.f, ay = 0.f, az = 0.f, aw = 0.f;
#pragma unroll
    for (int k = 0; k < 64; k++) {
        float xv = Xl[r][k];
        float4 w = Wl4[k][c4];
        ax += xv * w.x;
        ay += xv * w.y;
        az += xv * w.z;
        aw += xv * w.w;
    }
    int row = row0 + r;
    if (row < n) {
        float dv = dinv[row];
        Y4[(size_t)row * 16 + c4] = float4{ax * dv, ay * dv, az * dv, aw * dv};
    }
}

// H[i][:] = relu(dinv[i]*(Y[i][:] + sum_{in-edges} Y[src][:]) + b)
// One wave per node; 4 lane-groups of 16, float4/lane, x4 unroll (16 gathers in flight).
__global__ void aggregate_kernel(const float4* __restrict__ Y4, const int* __restrict__ sorted_src,
                                 const int* __restrict__ offsets, const float* __restrict__ dinv,
                                 const float4* __restrict__ bias4, float4* __restrict__ H4, int n) {
    int node = blockIdx.x * 4 + (threadIdx.x >> 6);
    if (node >= n) return;
    int lane = threadIdx.x & 63;
    int g = lane >> 4, q = lane & 15;
    int s = offsets[node], e = offsets[node + 1];
    float ax = 0.f, ay = 0.f, az = 0.f, aw = 0.f;
    float bx = 0.f, by = 0.f, bz = 0.f, bw = 0.f;
    float cx = 0.f, cy = 0.f, cz = 0.f, cw = 0.f;
    float dx = 0.f, dy = 0.f, dz = 0.f, dw = 0.f;
    int i = s + g;
    for (; i + 12 < e; i += 16) {
        int s0 = sorted_src[i];
        int s1 = sorted_src[i + 4];
        int s2 = sorted_src[i + 8];
        int s3 = sorted_src[i + 12];
        float4 v0 = Y4[(size_t)s0 * 16 + q];
        float4 v1 = Y4[(size_t)s1 * 16 + q];
        float4 v2 = Y4[(size_t)s2 * 16 + q];
        float4 v3 = Y4[(size_t)s3 * 16 + q];
        ax += v0.x; ay += v0.y; az += v0.z; aw += v0.w;
        bx += v1.x; by += v1.y; bz += v1.z; bw += v1.w;
        cx += v2.x; cy += v2.y; cz += v2.z; cw += v2.w;
        dx += v3.x; dy += v3.y; dz += v3.z; dw += v3.w;
    }
    for (; i < e; i += 4) {
        int sv = sorted_src[i];
        float4 v = Y4[(size_t)sv * 16 + q];
        ax += v.x; ay += v.y; az += v.z; aw += v.w;
    }
    ax += bx + cx + dx;
    ay += by + cy + dy;
    az += bz + cz + dz;
    aw += bw + cw + dw;
#pragma unroll
    for (int m = 16; m <= 32; m <<= 1) {
        ax += __shfl_xor(ax, m);
        ay += __shfl_xor(ay, m);
        az += __shfl_xor(az, m);
        aw += __shfl_xor(aw, m);
    }
    float4 self = Y4[(size_t)node * 16 + q];
    float dv = dinv[node];
    float4 b = bias4[q];
    float4 r;
    r.x = fmaxf(dv * (ax + self.x) + b.x, 0.f);
    r.y = fmaxf(dv * (ay + self.y) + b.y, 0.f);
    r.z = fmaxf(dv * (az + self.z) + b.z, 0.f);
    r.w = fmaxf(dv * (aw + self.w) + b.w, 0.f);
    if (g == 0) H4[(size_t)node * 16 + q] = r;
}

// ---------------- pooling + head ----------------

__global__ void pool_kernel(const float4* __restrict__ H4, const int* __restrict__ batch,
                            float* __restrict__ sums, int* __restrict__ cnts, int n) {
    int gw = (blockIdx.x * blockDim.x + threadIdx.x) >> 6;
    int lane = threadIdx.x & 63;
    int g = lane >> 4, q = lane & 15;
    int start = gw * 256;
    if (start >= n) return;
    int end = min(start + 256, n);
    float ax = 0.f, ay = 0.f, az = 0.f, aw = 0.f;
    int cur = -1, run = 0;
    for (int i = start + g; i < end; i += 4) {
        int b = batch[i];
        if (b != cur) {
            if (run > 0) {
                atomicAdd(&sums[cur * DF + q * 4 + 0], ax);
                atomicAdd(&sums[cur * DF + q * 4 + 1], ay);
                atomicAdd(&sums[cur * DF + q * 4 + 2], az);
                atomicAdd(&sums[cur * DF + q * 4 + 3], aw);
                if (q == 0) atomicAdd(&cnts[cur], run);
            }
            cur = b; run = 0;
            ax = ay = az = aw = 0.f;
        }
        float4 v = H4[(size_t)i * 16 + q];
        ax += v.x; ay += v.y; az += v.z; aw += v.w;
        run++;
    }
    if (run > 0) {
        atomicAdd(&sums[cur * DF + q * 4 + 0], ax);
        atomicAdd(&sums[cur * DF + q * 4 + 1], ay);
        atomicAdd(&sums[cur * DF + q * 4 + 2], az);
        atomicAdd(&sums[cur * DF + q * 4 + 3], aw);
        if (q == 0) atomicAdd(&cnts[cur], run);
    }
}

__global__ void final_kernel(const float* __restrict__ sums, const int* __restrict__ cnts,
                             const float* __restrict__ Wp, const float* __restrict__ bp,
                             float* __restrict__ out) {
    int g = blockIdx.x, j = threadIdx.x;
    __shared__ float hg[64];
    float c = fmaxf((float)cnts[g], 1.f);
    hg[j] = sums[g * DF + j] / c;
    __syncthreads();
    float acc = bp[j];
#pragma unroll
    for (int k = 0; k < 64; k++) acc += hg[k] * Wp[k * DF + j];
    out[g * DF + j] = acc;
}

// ---------------- launch ----------------

extern "C" void kernel_launch(void* const* d_in, const int* in_sizes, int n_in,
                              void* d_out, int out_size, void* d_ws, size_t ws_size,
                              hipStream_t stream) {
    const float* x     = (const float*)d_in[0];
    const int*   ei    = (const int*)d_in[1];
    const int*   batch = (const int*)d_in[2];
    const float* W1    = (const float*)d_in[3];
    const float* b1    = (const float*)d_in[4];
    const float* W2    = (const float*)d_in[5];
    const float* b2    = (const float*)d_in[6];
    const float* Wp    = (const float*)d_in[7];
    const float* bp    = (const float*)d_in[8];

    int N = in_sizes[0] / DF;
    int E = in_sizes[1] / 2;
    const int* src = ei;
    const int* dst = ei + E;
    int quadOK = ((E & 3) == 0 && (((uintptr_t)ei & 15) == 0)) ? 1 : 0;
    int cap = ((E / 4 + 1023) / 1024) * 1024;   // per-shard bucket capacity (~2x expected)

    char* ws = (char*)d_ws;
    auto alloc = [&](size_t bytes) {
        void* p = (void*)ws;
        ws += (bytes + 255) / 256 * 256;
        return p;
    };
    float* dinv     = (float*)alloc((size_t)N * 4);
    int*   counts   = (int*)alloc((size_t)N * 4);
    int*   offsets  = (int*)alloc((size_t)(N + 1) * 4);
    int*   cursor   = (int*)alloc((size_t)N * 4);
    int*   bsums    = (int*)alloc(1024 * 4);
    int*   boffs    = (int*)alloc(1024 * 4);
    int*   shardCur = (int*)alloc(256);
    int*   bsrc     = (int*)alloc((size_t)cap * 8 * 4);
    int*   bdst     = (int*)alloc((size_t)cap * 8 * 4);
    int*   ssrc     = (int*)alloc((size_t)E * 4);
    float* y        = (float*)alloc((size_t)N * DF * 4);
    float* h        = (float*)alloc((size_t)N * DF * 4);
    float* psums    = (float*)alloc(64 * DF * 4);   // 16 KB, 256-aligned
    int*   pcnt     = (int*)alloc(64 * 4);

    hipMemsetAsync(counts, 0, (size_t)N * 4, stream);
    hipMemsetAsync(shardCur, 0, 256, stream);
    hipMemsetAsync(psums, 0, 64 * DF * 4 + 256, stream);  // sums + cnts (contiguous)

    int B = (N + 1023) / 1024;
    partition_kernel<<<(E + TILE - 1) / TILE, 256, 0, stream>>>(src, dst, E, quadOK,
                                                                bsrc, bdst, shardCur, cap);
    hist2_kernel<<<512, 256, 0, stream>>>(bdst, shardCur, cap, counts);
    scan_a<<<B, 256, 0, stream>>>(counts, bsums, N);
    scan_b<<<1, 256, 0, stream>>>(bsums, boffs, offsets + N, B);
    scan_c<<<B, 256, 0, stream>>>(counts, boffs, offsets, cursor, dinv, N);
    scatter2_kernel<<<512, 256, 0, stream>>>(bsrc, bdst, shardCur, cap, cursor, ssrc);

    gemm_scale<<<(N + 15) / 16, 256, 0, stream>>>((const float4*)x, (const float4*)W1, dinv,
                                                  (float4*)y, N);
    aggregate_kernel<<<(N + 3) / 4, 256, 0, stream>>>((const float4*)y, ssrc, offsets, dinv,
                                                      (const float4*)b1, (float4*)h, N);
    gemm_scale<<<(N + 15) / 16, 256, 0, stream>>>((const float4*)h, (const float4*)W2, dinv,
                                                  (float4*)y, N);
    aggregate_kernel<<<(N + 3) / 4, 256, 0, stream>>>((const float4*)y, ssrc, offsets, dinv,
                                                      (const float4*)b2, (float4*)h, N);

    int waves = (N + 255) / 256;
    pool_kernel<<<(waves + 3) / 4, 256, 0, stream>>>((const float4*)h, batch, psums, pcnt, N);
    final_kernel<<<64, 64, 0, stream>>>(psums, pcnt, Wp, bp, (float*)d_out);
}